// Round 15
// baseline (394.520 us; speedup 1.0000x reference)
//
#include <hip/hip_runtime.h>
#include <hip/hip_bf16.h>

// RNN-T joint network. B=4 T=256 U=64 D=512 J=512 V=1024.
//   Pe = enc @ W_enc^T + b_enc   (1024 x 512)  fp32 in ws
//   Pd = dec @ W_dec^T           (256  x 512)  fp32 in ws (+ PdT k-major)
//   out[m,:] = tanh(Pe[m>>6] + Pd[(m>>14)*64 + (m&63)]) @ W_out^T + b_out
//
// gemm_joint (round-15): ZERO in-loop synchronization -- wave-private
// pipelines.
//   R3..R14: six sync structures all land at 150-190us, MfmaUtil 12-16%.
//   Shared mechanism: in-loop s_barriers phase-lock all waves (2 WGs run
//   identical code at identical rate -> stalls coincide; no covering).
//   m97's implicit overlap came from DRIFTING blocks. Fix: remove ALL
//   in-loop barriers. Each wave owns (a) a read-only full-K sH slice
//   (one prologue barrier), (b) a PRIVATE dbuf LDS B-buffer staged by
//   global_load_lds -- own-wave DMA -> own-wave ds_read needs only the
//   per-wave vmcnt retire (no barrier). K-loop/wave: 4 DMA, vmcnt(4),
//   8 ds_read, 8 MFMA (setprio). Waves drift; scheduler overlaps.
// Geometry: BM=64, BN=512 (nb=2, tanh x2), BK=32, 2048 blocks, 512 thr
// / 8 waves, wave-tile 64x64, acc[2][2] f32x16. LDS 128KB = sH 64KB
// ([c][64r][8] chunk-major, 0-conflict family) + 8x2x4KB private sB
// ([c][64n][8]). 1 WG/CU, 2 waves/SIMD. WT/PdT pre-transposes kept (R13/14).

typedef __attribute__((ext_vector_type(8))) short short8;     // 8 bf16
typedef __attribute__((ext_vector_type(4))) float f32x4;
typedef __attribute__((ext_vector_type(8))) float f32x8;
typedef __attribute__((ext_vector_type(16))) float f32x16;

#define SZ0 524288
#define SZ1 131072
#define SZ2 262144
#define SZ3 512
#define SZ4 262144
#define SZ5 524288
#define SZ6 1024
#define CU0 0
#define CU1 524288
#define CU2 655360
#define CU3 917504
#define CU4 918016
#define CU5 1180160
#define CU6 1704448
#define CTOT 1705472

// ---------------------------------------------------------------------------
// Runtime dtype detection (unchanged).
// ---------------------------------------------------------------------------
__global__ void detect_kernel(const void* p0, const void* p1, const void* p2,
                              const void* p3, const void* p4, const void* p5,
                              const void* p6, int* flags) {
  const void* ps[7] = {p0, p1, p2, p3, p4, p5, p6};
  const int sz[7] = {SZ0, SZ1, SZ2, SZ3, SZ4, SZ5, SZ6};
  const int w = threadIdx.x >> 6;
  const int l = threadIdx.x & 63;
  if (w >= 7) return;
  const unsigned short* u = (const unsigned short*)ps[w];
  const int lim = sz[w] < 1024 ? sz[w] : 1024;
  int bad = 0;
  for (int j = l; j < lim; j += 64) {
    const unsigned e = (u[j] >> 7) & 0xFFu;
    if (e >= 0x8Eu) bad = 1;
  }
  const unsigned long long b = __ballot(bad);
  if (l == 0) flags[w] = (b != 0ULL) ? 1 : 0;
}

__global__ __launch_bounds__(256) void convert_kernel(
    const void* p0, const void* p1, const void* p2, const void* p3,
    const void* p4, const void* p5, const void* p6,
    const int* __restrict__ flags, __hip_bfloat16* __restrict__ dst) {
  const int gid = blockIdx.x * 256 + threadIdx.x;
  if (gid >= CTOT) return;
  int t, local;
  const void* p;
  if (gid < CU1)      { t = 0; local = gid - CU0; p = p0; }
  else if (gid < CU2) { t = 1; local = gid - CU1; p = p1; }
  else if (gid < CU3) { t = 2; local = gid - CU2; p = p2; }
  else if (gid < CU4) { t = 3; local = gid - CU3; p = p3; }
  else if (gid < CU5) { t = 4; local = gid - CU4; p = p4; }
  else if (gid < CU6) { t = 5; local = gid - CU5; p = p5; }
  else                { t = 6; local = gid - CU6; p = p6; }
  __hip_bfloat16 v;
  if (flags[t])
    v = __float2bfloat16(((const float*)p)[local]);
  else
    v = ((const __hip_bfloat16*)p)[local];
  dst[gid] = v;
}

// ---------------------------------------------------------------------------
// m97-structure GEMM body for the two small projections. CT (optional):
// also write the transposed result CT[col*M + row] (used for PdT).
// ---------------------------------------------------------------------------
__device__ __forceinline__ void gemm_bt_body(
    const __hip_bfloat16* __restrict__ A, const __hip_bfloat16* __restrict__ Bw,
    const __hip_bfloat16* __restrict__ bias, float* __restrict__ C,
    float* __restrict__ CT, int M, int N, int K, int bid,
    __hip_bfloat16* sA, __hip_bfloat16* sB) {
  const int tid = threadIdx.x;
  const int w = tid >> 6;
  const int l = tid & 63;
  const int ntiles = N >> 7;
  const int mt = bid / ntiles;
  const int nt = bid % ntiles;
  const int m0 = mt << 7;
  const int n0 = nt << 7;
  const int wm = (w >> 1) << 6;
  const int wn = (w & 1) << 6;
  const int r16 = l & 15;
  const int q = l >> 4;

  f32x4 acc[4][4] = {};

  const int srow_in = l >> 3;
  const int scol = (l & 7) << 3;

  for (int k0 = 0; k0 < K; k0 += 64) {
#pragma unroll
    for (int i = 0; i < 4; ++i) {
      const int c = (w << 2) + i;
      const int row = (c << 3) + srow_in;
      const __hip_bfloat16* gA = A + (size_t)(m0 + row) * K + k0 + scol;
      const __hip_bfloat16* gB = Bw + (size_t)(n0 + row) * K + k0 + scol;
      __builtin_amdgcn_global_load_lds(
          (const __attribute__((address_space(1))) void*)gA,
          (__attribute__((address_space(3))) void*)(sA + (c << 9) + (l << 3)),
          16, 0, 0);
      __builtin_amdgcn_global_load_lds(
          (const __attribute__((address_space(1))) void*)gB,
          (__attribute__((address_space(3))) void*)(sB + (c << 9) + (l << 3)),
          16, 0, 0);
    }
    __syncthreads();

#pragma unroll
    for (int kk = 0; kk < 2; ++kk) {
      const int kc = (kk << 5) + (q << 3);
      short8 af[4], bf[4];
#pragma unroll
      for (int mi = 0; mi < 4; ++mi)
        af[mi] = *(const short8*)(sA + (wm + (mi << 4) + r16) * 64 + kc);
#pragma unroll
      for (int ni = 0; ni < 4; ++ni)
        bf[ni] = *(const short8*)(sB + (wn + (ni << 4) + r16) * 64 + kc);
#pragma unroll
      for (int mi = 0; mi < 4; ++mi)
#pragma unroll
        for (int ni = 0; ni < 4; ++ni)
          acc[mi][ni] = __builtin_amdgcn_mfma_f32_16x16x32_bf16(
              af[mi], bf[ni], acc[mi][ni], 0, 0, 0);
    }
    __syncthreads();
  }

#pragma unroll
  for (int ni = 0; ni < 4; ++ni) {
    const int col = n0 + wn + (ni << 4) + r16;
    const float bc = bias ? __bfloat162float(bias[col]) : 0.0f;
#pragma unroll
    for (int mi = 0; mi < 4; ++mi) {
      const int rowb = m0 + wm + (mi << 4) + (q << 2);
#pragma unroll
      for (int i = 0; i < 4; ++i) {
        const float v = acc[mi][ni][i] + bc;
        C[(size_t)(rowb + i) * N + col] = v;
        if (CT) CT[(size_t)col * M + rowb + i] = v;
      }
    }
  }
}

// proj blocks 0..31: Pe. 32..39: Pd (+PdT k-major epilogue).
// 40..47: W_out -> WT transpose, WT[(k>>3)*1024 + n][8] (chunk-major, 1MB).
__global__ __launch_bounds__(256) void proj_kernel(
    const __hip_bfloat16* __restrict__ enc, const __hip_bfloat16* __restrict__ Wenc,
    const __hip_bfloat16* __restrict__ benc,
    const __hip_bfloat16* __restrict__ dec, const __hip_bfloat16* __restrict__ Wdec,
    const __hip_bfloat16* __restrict__ Wout, __hip_bfloat16* __restrict__ WT,
    float* __restrict__ Pe, float* __restrict__ Pd, float* __restrict__ PdT) {
  __shared__ __align__(16) __hip_bfloat16 sA[128 * 64];
  __shared__ __align__(16) __hip_bfloat16 sB[128 * 64];
  if (blockIdx.x < 32) {
    gemm_bt_body(enc, Wenc, benc, Pe, nullptr, 1024, 512, 512, blockIdx.x,
                 sA, sB);
  } else if (blockIdx.x < 40) {
    gemm_bt_body(dec, Wdec, nullptr, Pd, PdT, 256, 512, 512, blockIdx.x - 32,
                 sA, sB);
  } else {
    const int bid = blockIdx.x - 40;            // 0..7
#pragma unroll
    for (int i = 0; i < 32; ++i) {
      const int cid = (bid << 13) + (i << 8) + threadIdx.x;  // 0..65535
      const int n = cid >> 6;
      const int c = cid & 63;
      *(short8*)(WT + (((size_t)c << 10) + n) * 8) =
          *(const short8*)(Wout + (size_t)n * 512 + (c << 3));
    }
  }
}

// ---------------------------------------------------------------------------
// Main fused GEMM, wave-private pipelines. grid = 2048 (1024 mb x 2 nb),
// 512 threads / 8 waves, wave-tile 64x64 (wave w owns cols wn..wn+64),
// acc[2][2] f32x16. 16 K-iters (BK=32). Per iter/wave: 4 gload_lds into
// OWN dbuf slice, s_waitcnt vmcnt(4) (own counter -- no barrier!),
// 8 ds_read, 8 MFMA. The only barrier in the kernel is after the sH fill.
// ---------------------------------------------------------------------------
__global__ __launch_bounds__(512, 2) void gemm_joint(
    const float* __restrict__ Pe, const float* __restrict__ PdT,
    const __hip_bfloat16* __restrict__ WT,
    const __hip_bfloat16* __restrict__ bias, float* __restrict__ out) {
  __shared__ __align__(16) __hip_bfloat16 sH[64 * 64 * 8];     // 64 KB
  __shared__ __align__(16) __hip_bfloat16 sBw[8][2][4 * 64 * 8];  // 8x2x4 KB

  const int t = threadIdx.x;
  const int w = t >> 6;
  const int l = t & 63;
  const int l31 = l & 31;
  const int q2 = l >> 5;
  const int mb = blockIdx.x >> 1;
  const int nb = blockIdx.x & 1;
  const int m0 = mb << 6;
  const int wn = (nb << 9) + (w << 6);   // this wave's global col base

  // Per-wave STAGE: own 64 cols x 32 k of WT -> own buffer. 4 instrs;
  // source 1KB contiguous per instr; dest = uniform + l*16 (rule m104).
  auto stage = [&](int kt, int b) {
#pragma unroll
    for (int c = 0; c < 4; ++c) {
      const __hip_bfloat16* src =
          WT + (((size_t)((kt << 2) + c) << 10) + wn + l) * 8;
      __builtin_amdgcn_global_load_lds(
          (const __attribute__((address_space(1))) void*)src,
          (__attribute__((address_space(3))) void*)(
              &sBw[w][b][0] + (((c << 6) + l) << 3)),
          16, 0, 0);
    }
  };

  stage(0, 0);

  // Prologue fill: sH[c][r][8] = tanh(Pe[mb][c*8+x] + PdT[...]), full K.
  // r = l (64 rows), c = j*8 + w. Pe read wave-uniform; PdT lane-contiguous
  // (256B/instr, 4 fully-used lines -- R13/R14-verified path).
  {
    const int r = l;
    const float* peR = Pe + (size_t)mb * 512;
    const float* pdTb = PdT + ((mb >> 8) << 6) + r;
#pragma unroll
    for (int j = 0; j < 8; ++j) {
      const int c = (j << 3) + w;
      const f32x8 a = *(const f32x8*)(peR + (c << 3));
      float pd[8];
#pragma unroll
      for (int x = 0; x < 8; ++x)
        pd[x] = pdTb[(size_t)((c << 3) + x) << 8];
      short8 hv;
#pragma unroll
      for (int x = 0; x < 8; ++x) {
        const float sv = a[x] + pd[x];
        const float u = __expf(2.0f * sv);
        const float tv = 1.0f - 2.0f * __builtin_amdgcn_rcpf(u + 1.0f);
        const __hip_bfloat16 hb = __float2bfloat16(tv);
        hv[x] = *(const short*)&hb;
      }
      *(short8*)(sH + ((size_t)((c << 6) + r) << 3)) = hv;
    }
  }
  asm volatile("s_waitcnt lgkmcnt(0)" ::: "memory");  // sH writes complete
  __builtin_amdgcn_sched_barrier(0);
  __builtin_amdgcn_s_barrier();   // the ONLY barrier: publish sH
  __builtin_amdgcn_sched_barrier(0);

  f32x16 acc[2][2] = {};

  for (int kt = 0; kt < 16; ++kt) {
    const int b = kt & 1;
    if (kt < 15) {
      stage(kt + 1, b ^ 1);                             // own buffer, no race
      asm volatile("s_waitcnt vmcnt(4)" ::: "memory");  // own stage(kt) landed
    } else {
      asm volatile("s_waitcnt vmcnt(0)" ::: "memory");
    }
    __builtin_amdgcn_sched_barrier(0);

    __builtin_amdgcn_s_setprio(1);
#pragma unroll
    for (int ss = 0; ss < 2; ++ss) {
      const int c = (kt << 2) + (ss << 1) + q2;   // sH chunk (global k/8)
      const int kc = (ss << 1) + q2;              // own-sB chunk
      short8 af[2], bf[2];
#pragma unroll
      for (int mi = 0; mi < 2; ++mi)
        af[mi] = *(const short8*)(sH + (((c << 6) + (mi << 5) + l31) << 3));
#pragma unroll
      for (int ni = 0; ni < 2; ++ni)
        bf[ni] = *(const short8*)(&sBw[w][b][0] +
                                  (((kc << 6) + (ni << 5) + l31) << 3));
#pragma unroll
      for (int mi = 0; mi < 2; ++mi)
#pragma unroll
        for (int ni = 0; ni < 2; ++ni)
          acc[mi][ni] = __builtin_amdgcn_mfma_f32_32x32x16_bf16(
              af[mi], bf[ni], acc[mi][ni], 0, 0, 0);
    }
    __builtin_amdgcn_s_setprio(0);
    // no end-of-iter barrier: buffer b is re-staged only at iter kt+2,
    // and this wave (the sole reader) has consumed it by then.
  }

  // Epilogue: C/D layout (harness-verified R4..R14):
  // col = l&31, row = (rr&3) + 8*(rr>>2) + 4*q2.
#pragma unroll
  for (int ni = 0; ni < 2; ++ni) {
    const int col = wn + (ni << 5) + l31;
    const float bc = __bfloat162float(bias[col]);
#pragma unroll
    for (int mi = 0; mi < 2; ++mi) {
#pragma unroll
      for (int rr = 0; rr < 16; ++rr) {
        const int row = m0 + (mi << 5) + (rr & 3) + ((rr >> 2) << 3) +
                        (q2 << 2);
        out[(size_t)row * 1024 + col] = acc[mi][ni][rr] + bc;
      }
    }
  }
}

// ---------------------------------------------------------------------------
extern "C" void kernel_launch(void* const* d_in, const int* in_sizes, int n_in,
                              void* d_out, int out_size, void* d_ws,
                              size_t ws_size, hipStream_t stream) {
  // ws: 0 flags | 256 bf16 copies (3.41MB) | 4MB Pe (2MB) | 6MB Pd (0.5MB)
  //     | 8MB WT (1MB) | 9MB PdT (0.5MB, k-major fp32 transpose of Pd)
  char* ws = (char*)d_ws;
  int* flags = (int*)ws;
  __hip_bfloat16* cp = (__hip_bfloat16*)(ws + 256);
  float* Pe = (float*)(ws + (4ull << 20));
  float* Pd = (float*)(ws + (6ull << 20));
  __hip_bfloat16* WT = (__hip_bfloat16*)(ws + (8ull << 20));
  float* PdT = (float*)(ws + (9ull << 20));

  detect_kernel<<<dim3(1), dim3(512), 0, stream>>>(
      d_in[0], d_in[1], d_in[2], d_in[3], d_in[4], d_in[5], d_in[6], flags);
  convert_kernel<<<dim3((CTOT + 255) / 256), dim3(256), 0, stream>>>(
      d_in[0], d_in[1], d_in[2], d_in[3], d_in[4], d_in[5], d_in[6], flags, cp);

  const __hip_bfloat16* enc_c = cp + CU0;
  const __hip_bfloat16* dec_c = cp + CU1;
  const __hip_bfloat16* Wenc_c = cp + CU2;
  const __hip_bfloat16* benc_c = cp + CU3;
  const __hip_bfloat16* Wdec_c = cp + CU4;
  const __hip_bfloat16* Wout_c = cp + CU5;
  const __hip_bfloat16* bout_c = cp + CU6;

  proj_kernel<<<dim3(48), dim3(256), 0, stream>>>(
      enc_c, Wenc_c, benc_c, dec_c, Wdec_c, Wout_c, WT, Pe, Pd, PdT);
  gemm_joint<<<dim3(2048), dim3(512), 0, stream>>>(
      Pe, PdT, WT, bout_c, (float*)d_out);
}